// Round 13
// baseline (536.063 us; speedup 1.0000x reference)
//
#include <hip/hip_runtime.h>

// LoRALinear: out[8192,4096] = x @ W.T + 2.0*(x@A.T)@B.T = x @ (W + 2*B@A).T
// One bf16 MFMA GEMM. Faithful m201 8-phase reconstruction: 256x256 tile,
// 8 waves, BK=64, fixed-role bufs P(even)/Q(odd), 1 half-tile stage/phase,
// 8/8/8/0 smoothed reads with one-phase lookahead, vmcnt(6) once per tile.

#define N_ROWS 8192
#define K_DIM  4096
#define N_COLS 4096
#define RANK   16
#define BK     64
#define NT     (K_DIM / BK)   // 64 K-tiles

#define XBLK ((N_ROWS * K_DIM / 4) / 256)   // 32768 blocks for x->bf16
#define WBLK ((N_COLS * K_DIM / 4) / 256)   // 16384 blocks for W_eff->bf16

typedef __bf16 bf16x8 __attribute__((ext_vector_type(8)));
typedef float  f32x4  __attribute__((ext_vector_type(4)));

__device__ __forceinline__ unsigned short f2bf(float f) {
  unsigned int u = __builtin_bit_cast(unsigned int, f);
  u += 0x7FFFu + ((u >> 16) & 1u);   // RNE
  return (unsigned short)(u >> 16);
}

// ---------------- fused conversion kernel ----------------

__global__ __launch_bounds__(256) void prep_kernel(const float* __restrict__ x,
                                                   const float* __restrict__ w,
                                                   const float* __restrict__ A,
                                                   const float* __restrict__ Bm,
                                                   unsigned short* __restrict__ xb,
                                                   unsigned short* __restrict__ wb) {
  const int b = blockIdx.x;
  if (b < XBLK) {
    size_t idx = (size_t)b * 256 + threadIdx.x;
    const float4 v = *reinterpret_cast<const float4*>(x + idx * 4);
    ushort4 r;
    r.x = f2bf(v.x); r.y = f2bf(v.y); r.z = f2bf(v.z); r.w = f2bf(v.w);
    *reinterpret_cast<ushort4*>(xb + idx * 4) = r;
  } else {
    size_t idx = (size_t)(b - XBLK) * 256 + threadIdx.x;
    int o  = (int)(idx >> 10);
    int ic = (int)(idx & 1023) << 2;
    const float4 wv = *reinterpret_cast<const float4*>(w + (size_t)o * K_DIM + ic);
    float a0 = wv.x, a1 = wv.y, a2 = wv.z, a3 = wv.w;
    float br[RANK];
#pragma unroll
    for (int r4 = 0; r4 < RANK / 4; ++r4) {
      const float4 bv = *reinterpret_cast<const float4*>(Bm + (size_t)o * RANK + r4 * 4);
      br[r4 * 4 + 0] = bv.x; br[r4 * 4 + 1] = bv.y;
      br[r4 * 4 + 2] = bv.z; br[r4 * 4 + 3] = bv.w;
    }
#pragma unroll
    for (int r = 0; r < RANK; ++r) {
      const float4 av = *reinterpret_cast<const float4*>(A + (size_t)r * K_DIM + ic);
      float b2 = br[r] * 2.0f;
      a0 += b2 * av.x; a1 += b2 * av.y; a2 += b2 * av.z; a3 += b2 * av.w;
    }
    ushort4 rr;
    rr.x = f2bf(a0); rr.y = f2bf(a1); rr.z = f2bf(a2); rr.w = f2bf(a3);
    *reinterpret_cast<ushort4*>(wb + (size_t)o * K_DIM + ic) = rr;
  }
}

// ---------------- GEMM ----------------
// LDS: buf R (R=0:P @0, R=1:Q @65536), each 64KB:
//   A0 @+0, A1 @+16384, B0 @+32768, B1 @+49152  (each 16KB = 128 rows x 64 k)
// XOR swizzle within a half (16B granules): phys = logical ^ (row&7); staged
// via pre-swizzled global source (linear gload_lds dest), read w/ matching XOR.
// Group for tile t (R = t&1, other = R^1), 4 phases:
//  ph_a: rd B0,B1(t)<-R [8]; stg A0(t+2)->R; MFMA a0*b0 (Q1: mf0-3 x nf0-1)
//  ph_b: rd A1(t)  <-R [8]; stg B0(t+2)->R; MFMA a0*b1 (Q2: mf0-3 x nf2-3)
//  ph_c: rd A0(t+1)<-R^ [8]; stg A1(t+2)->R; MFMA a1*b1 (Q3: mf4-7 x nf2-3)
//  ph_d:                    stg B1(t+2)->R; MFMA a1*b0 (Q4); vmcnt(6)
// a0 loop-carried (read ph_c, consumed next group ph_a/ph_b). FIFO-verified:
// each read's data confirmed by a {vmcnt(6)->barrier} in an earlier phase.

__device__ __forceinline__ void gload_lds16(const void* g, void* l) {
  __builtin_amdgcn_global_load_lds(
      (__attribute__((address_space(1))) void*)g,
      (__attribute__((address_space(3))) void*)l, 16, 0, 0);
}

__global__ __launch_bounds__(512, 1) void gemm_bf16_r13(
    const unsigned short* __restrict__ xb, const unsigned short* __restrict__ wb,
    float* __restrict__ out) {
  __shared__ __align__(16) char smem[131072];

  const int t  = threadIdx.x;
  const int l  = t & 63;
  const int wv = t >> 6;
  const int lr = l & 15;
  const int lk = l >> 4;
  const int wr = wv >> 2;     // 0..1
  const int wc = wv & 3;      // 0..3

  // XCD-aware bijective swizzle: 512 blocks % 8 == 0
  const int bid  = blockIdx.x;
  const int sbid = (bid & 7) * 64 + (bid >> 3);
  const int bm   = sbid >> 4;   // 0..31
  const int bn   = sbid & 15;   // 0..15

  // staging: thread t -> row t>>3 (0..63), swizzled col granule
  const int srow = t >> 3;
  const int scol = ((t & 7) ^ ((t >> 3) & 7)) << 3;         // elements
  const unsigned short* gA = xb + (size_t)(bm * 256 + srow) * K_DIM + scol;
  const unsigned short* gB = wb + (size_t)(bn * 256 + srow) * K_DIM + scol;

  // stage one 128-row half-tile (2 gloads) to LDS byte offset OFF
#define STG_HALF(OFF, SRC) do {                                                 \
    char* _l = smem + (OFF) + t * 16;                                           \
    gload_lds16((SRC), _l);                                                     \
    gload_lds16((SRC) + (size_t)64 * K_DIM, _l + 8192);                         \
  } while (0)

  // fragment read addressing (read-side XOR matches staged swizzle)
  const int g0   = (lk ^ (lr & 7)) << 4;
  const int g1   = ((lk + 4) ^ (lr & 7)) << 4;
  const int aoff = (wr * 16 + lr) * 128;
  const int boff = (wc * 16 + lr) * 128;

  bf16x8 a0[8], a1[8], b0[4], b1[4];
  f32x4 acc[8][4];
#pragma unroll
  for (int m = 0; m < 8; ++m)
#pragma unroll
    for (int n = 0; n < 4; ++n)
      acc[m][n] = (f32x4){0.f, 0.f, 0.f, 0.f};

#define RD_A(DST, BASE) do {                                                    \
    _Pragma("unroll")                                                           \
    for (int m = 0; m < 4; ++m) {                                               \
      DST[2 * m + 0] = *(const bf16x8*)(smem + (BASE) + m * 4096 + aoff + g0);  \
      DST[2 * m + 1] = *(const bf16x8*)(smem + (BASE) + m * 4096 + aoff + g1);  \
    }                                                                           \
  } while (0)
#define RD_B(DST, BASE) do {                                                    \
    _Pragma("unroll")                                                           \
    for (int n = 0; n < 2; ++n) {                                               \
      DST[2 * n + 0] = *(const bf16x8*)(smem + (BASE) + n * 8192 + boff + g0);  \
      DST[2 * n + 1] = *(const bf16x8*)(smem + (BASE) + n * 8192 + boff + g1);  \
    }                                                                           \
  } while (0)

#define MFMA_Q(MB, AF, NB0, BF) do {                                            \
    _Pragma("unroll")                                                           \
    for (int mi = 0; mi < 4; ++mi)                                              \
      _Pragma("unroll")                                                         \
      for (int ni = 0; ni < 2; ++ni)                                            \
        _Pragma("unroll")                                                       \
        for (int kk = 0; kk < 2; ++kk)                                          \
          acc[(MB) + mi][(NB0) + ni] = __builtin_amdgcn_mfma_f32_16x16x32_bf16( \
              AF[mi * 2 + kk], BF[ni * 2 + kk], acc[(MB) + mi][(NB0) + ni], 0, 0, 0); \
  } while (0)

#define PH_PRE() do {                                                           \
    __builtin_amdgcn_sched_barrier(0);                                          \
    __builtin_amdgcn_s_barrier();                                               \
    asm volatile("s_waitcnt lgkmcnt(0)");                                       \
    __builtin_amdgcn_sched_barrier(0);                                          \
    __builtin_amdgcn_s_setprio(1);                                              \
  } while (0)
#define PH_POST() do {                                                          \
    __builtin_amdgcn_s_setprio(0);                                              \
    __builtin_amdgcn_sched_barrier(0);                                          \
    __builtin_amdgcn_s_barrier();                                               \
    __builtin_amdgcn_sched_barrier(0);                                          \
  } while (0)
#define PH_POST_VM6() do {                                                      \
    __builtin_amdgcn_s_setprio(0);                                              \
    __builtin_amdgcn_sched_barrier(0);                                          \
    asm volatile("s_waitcnt vmcnt(6)");                                         \
    __builtin_amdgcn_s_barrier();                                               \
    __builtin_amdgcn_sched_barrier(0);                                          \
  } while (0)

#define GROUP(RB, OB, T) do {                                                   \
    const int _ts = ((T) + 2 < NT) ? (T) + 2 : NT - 1;                          \
    const unsigned short* _sA = gA + (size_t)_ts * BK;                          \
    const unsigned short* _sB = gB + (size_t)_ts * BK;                          \
    /* ph_a: rd b0,b1(T); stg A0(ts); MFMA Q1 */                                \
    RD_B(b0, (RB) + 32768);                                                     \
    RD_B(b1, (RB) + 49152);                                                     \
    STG_HALF((RB) + 0, _sA);                                                    \
    PH_PRE(); MFMA_Q(0, a0, 0, b0); PH_POST();                                  \
    /* ph_b: rd a1(T); stg B0(ts); MFMA Q2 */                                   \
    RD_A(a1, (RB) + 16384);                                                     \
    STG_HALF((RB) + 32768, _sB);                                                \
    PH_PRE(); MFMA_Q(0, a0, 2, b1); PH_POST();                                  \
    /* ph_c: rd a0(T+1)<-other buf; stg A1(ts); MFMA Q3 */                      \
    RD_A(a0, (OB) + 0);                                                         \
    STG_HALF((RB) + 16384, _sA + (size_t)128 * K_DIM);                          \
    PH_PRE(); MFMA_Q(4, a1, 2, b1); PH_POST();                                  \
    /* ph_d: stg B1(ts); MFMA Q4; vmcnt(6) */                                   \
    STG_HALF((RB) + 49152, _sB + (size_t)128 * K_DIM);                          \
    PH_PRE(); MFMA_Q(4, a1, 0, b0); PH_POST_VM6();                              \
  } while (0)

  // ---- prologue: stage tile0 -> P, tile1 -> Q; full drain; pre-read a0(0)
  STG_HALF(0,     gA);
  STG_HALF(16384, gA + (size_t)128 * K_DIM);
  STG_HALF(32768, gB);
  STG_HALF(49152, gB + (size_t)128 * K_DIM);
  {
    const unsigned short* g1A = gA + (size_t)BK;
    const unsigned short* g1B = gB + (size_t)BK;
    STG_HALF(65536 + 0,     g1A);
    STG_HALF(65536 + 16384, g1A + (size_t)128 * K_DIM);
    STG_HALF(65536 + 32768, g1B);
    STG_HALF(65536 + 49152, g1B + (size_t)128 * K_DIM);
  }
  __builtin_amdgcn_sched_barrier(0);
  asm volatile("s_waitcnt vmcnt(0)");
  __builtin_amdgcn_s_barrier();
  __builtin_amdgcn_sched_barrier(0);
  RD_A(a0, 0);   // P.A0 = tile 0

#pragma nounroll
  for (int u = 0; u < NT / 2; ++u) {
    GROUP(0,     65536, 2 * u);
    GROUP(65536, 0,     2 * u + 1);
  }

  // ---- epilogue: C/D layout col=lane&15, row=(lane>>4)*4+j ----
  const int orow = bm * 256 + wr * 16 + lk * 4;
  const int ocol = bn * 256 + wc * 16 + lr;
#pragma unroll
  for (int mf = 0; mf < 8; ++mf)
#pragma unroll
    for (int nf = 0; nf < 4; ++nf)
#pragma unroll
      for (int j = 0; j < 4; ++j)
        out[(size_t)(orow + mf * 32 + j) * N_COLS + (ocol + nf * 64)] = acc[mf][nf][j];

#undef STG_HALF
#undef RD_A
#undef RD_B
#undef MFMA_Q
#undef PH_PRE
#undef PH_POST
#undef PH_POST_VM6
#undef GROUP
}

// ---------------- exact fp32 fallback (ws too small) ----------------

__global__ __launch_bounds__(256) void fallback_kernel(const float* __restrict__ x,
                                                       const float* __restrict__ w,
                                                       const float* __restrict__ A,
                                                       const float* __restrict__ Bm,
                                                       float* __restrict__ out) {
  const int o    = blockIdx.x * 256 + threadIdx.x;
  const int nrow = blockIdx.y;
  float bro[RANK];
#pragma unroll
  for (int r = 0; r < RANK; ++r) bro[r] = Bm[(size_t)o * RANK + r] * 2.0f;
  float bacc = 0.f;
  float tacc[RANK];
#pragma unroll
  for (int r = 0; r < RANK; ++r) tacc[r] = 0.f;
  for (int k = 0; k < K_DIM; ++k) {
    float xv = x[(size_t)nrow * K_DIM + k];
    bacc += xv * w[(size_t)o * K_DIM + k];
#pragma unroll
    for (int r = 0; r < RANK; ++r) tacc[r] += xv * A[(size_t)r * K_DIM + k];
  }
  float res = bacc;
#pragma unroll
  for (int r = 0; r < RANK; ++r) res += bro[r] * tacc[r];
  out[(size_t)nrow * N_COLS + o] = res;
}

// ---------------- launch ----------------

extern "C" void kernel_launch(void* const* d_in, const int* in_sizes, int n_in,
                              void* d_out, int out_size, void* d_ws, size_t ws_size,
                              hipStream_t stream) {
  const float* x  = (const float*)d_in[0];
  const float* w  = (const float*)d_in[1];
  const float* A  = (const float*)d_in[2];
  const float* Bm = (const float*)d_in[3];
  float* out = (float*)d_out;

  const size_t need = ((size_t)N_ROWS * K_DIM + (size_t)N_COLS * K_DIM) * sizeof(unsigned short);
  if (ws_size < need) {
    dim3 grid(N_COLS / 256, N_ROWS);
    fallback_kernel<<<grid, 256, 0, stream>>>(x, w, A, Bm, out);
    return;
  }

  unsigned short* xb = (unsigned short*)d_ws;
  unsigned short* wb = xb + (size_t)N_ROWS * K_DIM;

  prep_kernel<<<XBLK + WBLK, 256, 0, stream>>>(x, w, A, Bm, xb, wb);

  const int grid_gemm = (N_ROWS / 256) * (N_COLS / 256);   // 512
  gemm_bf16_r13<<<grid_gemm, 512, 0, stream>>>(xb, wb, out);
}

// Round 14
// 346.246 us; speedup vs baseline: 1.5482x; 1.5482x over previous
//
#include <hip/hip_runtime.h>

// LoRALinear: out[8192,4096] = x @ W.T + 2.0*(x@A.T)@B.T = x @ (W + 2*B@A).T
// One bf16 MFMA GEMM. R14 = R8's proven skeleton (256x256, 8 waves, BK=64,
// one barrier per K-tile, stage-first, vmcnt(0) tile drain) with 32x32x16
// MFMA and wave-tile 64x128 (4x2 wave grid): 8 independent acc chains of 4,
// 256 MFMA/CU/tile @8.07cyc = 2066 cyc vs 2484 for 16x16x32 (-17%).

#define N_ROWS 8192
#define K_DIM  4096
#define N_COLS 4096
#define RANK   16
#define BK     64
#define NT     (K_DIM / BK)   // 64 K-tiles

#define XBLK ((N_ROWS * K_DIM / 4) / 256)   // 32768 blocks for x->bf16
#define WBLK ((N_COLS * K_DIM / 4) / 256)   // 16384 blocks for W_eff->bf16

typedef __bf16 bf16x8 __attribute__((ext_vector_type(8)));
typedef float  f32x16 __attribute__((ext_vector_type(16)));

__device__ __forceinline__ unsigned short f2bf(float f) {
  unsigned int u = __builtin_bit_cast(unsigned int, f);
  u += 0x7FFFu + ((u >> 16) & 1u);   // RNE
  return (unsigned short)(u >> 16);
}

// ---------------- fused conversion kernel ----------------

__global__ __launch_bounds__(256) void prep_kernel(const float* __restrict__ x,
                                                   const float* __restrict__ w,
                                                   const float* __restrict__ A,
                                                   const float* __restrict__ Bm,
                                                   unsigned short* __restrict__ xb,
                                                   unsigned short* __restrict__ wb) {
  const int b = blockIdx.x;
  if (b < XBLK) {
    size_t idx = (size_t)b * 256 + threadIdx.x;
    const float4 v = *reinterpret_cast<const float4*>(x + idx * 4);
    ushort4 r;
    r.x = f2bf(v.x); r.y = f2bf(v.y); r.z = f2bf(v.z); r.w = f2bf(v.w);
    *reinterpret_cast<ushort4*>(xb + idx * 4) = r;
  } else {
    size_t idx = (size_t)(b - XBLK) * 256 + threadIdx.x;
    int o  = (int)(idx >> 10);
    int ic = (int)(idx & 1023) << 2;
    const float4 wv = *reinterpret_cast<const float4*>(w + (size_t)o * K_DIM + ic);
    float a0 = wv.x, a1 = wv.y, a2 = wv.z, a3 = wv.w;
    float br[RANK];
#pragma unroll
    for (int r4 = 0; r4 < RANK / 4; ++r4) {
      const float4 bv = *reinterpret_cast<const float4*>(Bm + (size_t)o * RANK + r4 * 4);
      br[r4 * 4 + 0] = bv.x; br[r4 * 4 + 1] = bv.y;
      br[r4 * 4 + 2] = bv.z; br[r4 * 4 + 3] = bv.w;
    }
#pragma unroll
    for (int r = 0; r < RANK; ++r) {
      const float4 av = *reinterpret_cast<const float4*>(A + (size_t)r * K_DIM + ic);
      float b2 = br[r] * 2.0f;
      a0 += b2 * av.x; a1 += b2 * av.y; a2 += b2 * av.z; a3 += b2 * av.w;
    }
    ushort4 rr;
    rr.x = f2bf(a0); rr.y = f2bf(a1); rr.z = f2bf(a2); rr.w = f2bf(a3);
    *reinterpret_cast<ushort4*>(wb + (size_t)o * K_DIM + ic) = rr;
  }
}

// ---------------- GEMM ----------------
// LDS: A [buf][half][128 rows][64 k] bf16 at 0..64K; B same at 64K..128K
// (identical to R8). XOR swizzle within a half (16B granules):
// phys = logical ^ (row&7); staged via pre-swizzled global source (linear
// gload_lds dest), read with matching XOR.
// 32x32x16 geometry, wave grid wm=wv>>1 (0..3), wn=wv&1 (0..1):
//   A row  = wm*64 + mf*32 + (l&31)   (mf 0..1)   half = wm>>1
//   B row  = wn*128 + nf*32 + (l&31)  (nf 0..3)   half = wn
//   operand k-granule g = 2*kk + (l>>5), XOR (l&7)   [R11-verified layout]
//   C/D: col = l&31, row = (reg&3) + 8*(reg>>2) + 4*(l>>5)  [m74/m101]
// Per tile t: stage 4 half-tiles(t+1)->buf n (8 gloads, issue-first); free
// compiler-scheduled interior (24 ds_read_b128 + 32 MFMA, 8 indep chains);
// lgkm(0); vmcnt(0); s_barrier.  (R8's proven sync, unchanged.)

__device__ __forceinline__ void gload_lds16(const void* g, void* l) {
  __builtin_amdgcn_global_load_lds(
      (__attribute__((address_space(1))) void*)g,
      (__attribute__((address_space(3))) void*)l, 16, 0, 0);
}

__global__ __launch_bounds__(512, 1) void gemm_bf16_r14(
    const unsigned short* __restrict__ xb, const unsigned short* __restrict__ wb,
    float* __restrict__ out) {
  __shared__ __align__(16) char smem[131072];

  const int t   = threadIdx.x;
  const int l   = t & 63;
  const int wv  = t >> 6;
  const int l31 = l & 31;
  const int l5  = l >> 5;     // 0..1
  const int wm  = wv >> 1;    // 0..3 (64-row slabs)
  const int wn  = wv & 1;     // 0..1 (128-col slabs)

  // XCD-aware bijective swizzle: 512 blocks % 8 == 0
  const int bid  = blockIdx.x;
  const int sbid = (bid & 7) * 64 + (bid >> 3);
  const int bm   = sbid >> 4;   // 0..31
  const int bn   = sbid & 15;   // 0..15

  // staging: thread t -> row t>>3 (0..63), swizzled col granule (R8-verified)
  const int srow = t >> 3;
  const int scol = ((t & 7) ^ ((t >> 3) & 7)) << 3;         // elements
  const unsigned short* gA = xb + (size_t)(bm * 256 + srow) * K_DIM + scol;
  const unsigned short* gB = wb + (size_t)(bn * 256 + srow) * K_DIM + scol;
  char* ldsA = smem + t * 16;
  char* ldsB = smem + 65536 + t * 16;

#define STG_A(hh, SRC, NB) do {                                                 \
    const unsigned short* _g = (SRC) + (size_t)((hh) * 128) * K_DIM;            \
    char* _l = ldsA + (NB) + (hh) * 16384;                                      \
    gload_lds16(_g, _l);                                                        \
    gload_lds16(_g + (size_t)64 * K_DIM, _l + 8192);                            \
  } while (0)
#define STG_B(hh, SRC, NB) do {                                                 \
    const unsigned short* _g = (SRC) + (size_t)((hh) * 128) * K_DIM;            \
    char* _l = ldsB + (NB) + (hh) * 16384;                                      \
    gload_lds16(_g, _l);                                                        \
    gload_lds16(_g + (size_t)64 * K_DIM, _l + 8192);                            \
  } while (0)

  // fragment read addressing: granule g = 2*kk + l5, XOR (l31&7)
  const int gr0 = ((0 + l5) ^ (l31 & 7)) << 4;   // kk=0
  const int gr1 = ((2 + l5) ^ (l31 & 7)) << 4;   // kk=1
  const int gr2 = ((4 + l5) ^ (l31 & 7)) << 4;   // kk=2
  const int gr3 = ((6 + l5) ^ (l31 & 7)) << 4;   // kk=3
  // A: half (wm>>1)*16384, rowIn128 = (wm&1)*64 + mf*32 + l31
  const int a_base = (wm >> 1) * 16384 + (wm & 1) * 8192 + l31 * 128;  // + mf*4096
  // B: half wn*16384, rowIn128 = nf*32 + l31
  const int b_base = 65536 + wn * 16384 + l31 * 128;                   // + nf*4096

  bf16x8 aF[8];    // 2 mf x 4 kk
  bf16x8 bF[16];   // 4 nf x 4 kk
  f32x16 acc[2][4];
#pragma unroll
  for (int m = 0; m < 2; ++m)
#pragma unroll
    for (int n = 0; n < 4; ++n)
#pragma unroll
      for (int e = 0; e < 16; ++e)
        acc[m][n][e] = 0.f;

#define RD_A(CB_) do {                                                          \
    _Pragma("unroll")                                                           \
    for (int m = 0; m < 2; ++m) {                                               \
      const char* _p = smem + (CB_) + a_base + m * 4096;                        \
      aF[4 * m + 0] = *(const bf16x8*)(_p + gr0);                               \
      aF[4 * m + 1] = *(const bf16x8*)(_p + gr1);                               \
      aF[4 * m + 2] = *(const bf16x8*)(_p + gr2);                               \
      aF[4 * m + 3] = *(const bf16x8*)(_p + gr3);                               \
    }                                                                           \
  } while (0)
#define RD_B2(NF0, CB_) do {                                                    \
    _Pragma("unroll")                                                           \
    for (int n = 0; n < 2; ++n) {                                               \
      const char* _p = smem + (CB_) + b_base + ((NF0) + n) * 4096;              \
      bF[4 * ((NF0) + n) + 0] = *(const bf16x8*)(_p + gr0);                     \
      bF[4 * ((NF0) + n) + 1] = *(const bf16x8*)(_p + gr1);                     \
      bF[4 * ((NF0) + n) + 2] = *(const bf16x8*)(_p + gr2);                     \
      bF[4 * ((NF0) + n) + 3] = *(const bf16x8*)(_p + gr3);                     \
    }                                                                           \
  } while (0)

#define MFMA_N2(NF0) do {                                                       \
    _Pragma("unroll")                                                           \
    for (int mi = 0; mi < 2; ++mi)                                              \
      _Pragma("unroll")                                                         \
      for (int ni = 0; ni < 2; ++ni)                                            \
        _Pragma("unroll")                                                       \
        for (int kk = 0; kk < 4; ++kk)                                          \
          acc[mi][(NF0) + ni] = __builtin_amdgcn_mfma_f32_32x32x16_bf16(        \
              aF[mi * 4 + kk], bF[4 * ((NF0) + ni) + kk],                       \
              acc[mi][(NF0) + ni], 0, 0, 0);                                    \
  } while (0)

#define TILE(CB, NB, T) do {                                                    \
    const int _t1 = ((T) + 1 < NT) ? (T) + 1 : NT - 1;                          \
    const unsigned short* _sA = gA + (size_t)_t1 * BK;                          \
    const unsigned short* _sB = gB + (size_t)_t1 * BK;                          \
    /* issue-first staging of t+1 into buf n */                                 \
    STG_A(0, _sA, NB); STG_A(1, _sA, NB);                                       \
    STG_B(0, _sB, NB); STG_B(1, _sB, NB);                                       \
    __builtin_amdgcn_sched_barrier(0);                                          \
    /* free interior: compiler interleaves reads & MFMAs w/ counted lgkmcnt */  \
    RD_A((CB));                                                                 \
    RD_B2(0, (CB));                                                             \
    MFMA_N2(0);                                                                 \
    RD_B2(2, (CB));                                                             \
    MFMA_N2(2);                                                                 \
    /* tile-end fence: own reads drained, own stages landed, then barrier */    \
    asm volatile("s_waitcnt lgkmcnt(0)");                                       \
    __builtin_amdgcn_sched_barrier(0);                                          \
    asm volatile("s_waitcnt vmcnt(0)");                                         \
    __builtin_amdgcn_s_barrier();                                               \
    __builtin_amdgcn_sched_barrier(0);                                          \
  } while (0)

  // ---- prologue: stage tile0 -> buf0; drain; barrier ----
  STG_A(0, gA, 0); STG_A(1, gA, 0); STG_B(0, gB, 0); STG_B(1, gB, 0);
  __builtin_amdgcn_sched_barrier(0);
  asm volatile("s_waitcnt vmcnt(0)");
  __builtin_amdgcn_s_barrier();
  __builtin_amdgcn_sched_barrier(0);

#pragma nounroll
  for (int u = 0; u < NT / 2; ++u) {
    TILE(0, 32768, 2 * u);
    TILE(32768, 0, 2 * u + 1);
  }

  // ---- epilogue: C/D col=l&31, row=(reg&3)+8*(reg>>2)+4*(l>>5) [verified] --
  const int orow = bm * 256 + wm * 64 + l5 * 4;
  const int ocol = bn * 256 + wn * 128 + l31;
#pragma unroll
  for (int mf = 0; mf < 2; ++mf)
#pragma unroll
    for (int nf = 0; nf < 4; ++nf)
#pragma unroll
      for (int reg = 0; reg < 16; ++reg) {
        const int row = orow + mf * 32 + (reg & 3) + 8 * (reg >> 2);
        out[(size_t)row * N_COLS + (ocol + nf * 32)] = acc[mf][nf][reg];
      }

#undef STG_A
#undef STG_B
#undef RD_A
#undef RD_B2
#undef MFMA_N2
#undef TILE
}

// ---------------- exact fp32 fallback (ws too small) ----------------

__global__ __launch_bounds__(256) void fallback_kernel(const float* __restrict__ x,
                                                       const float* __restrict__ w,
                                                       const float* __restrict__ A,
                                                       const float* __restrict__ Bm,
                                                       float* __restrict__ out) {
  const int o    = blockIdx.x * 256 + threadIdx.x;
  const int nrow = blockIdx.y;
  float bro[RANK];
#pragma unroll
  for (int r = 0; r < RANK; ++r) bro[r] = Bm[(size_t)o * RANK + r] * 2.0f;
  float bacc = 0.f;
  float tacc[RANK];
#pragma unroll
  for (int r = 0; r < RANK; ++r) tacc[r] = 0.f;
  for (int k = 0; k < K_DIM; ++k) {
    float xv = x[(size_t)nrow * K_DIM + k];
    bacc += xv * w[(size_t)o * K_DIM + k];
#pragma unroll
    for (int r = 0; r < RANK; ++r) tacc[r] += xv * A[(size_t)r * K_DIM + k];
  }
  float res = bacc;
#pragma unroll
  for (int r = 0; r < RANK; ++r) res += bro[r] * tacc[r];
  out[(size_t)nrow * N_COLS + o] = res;
}

// ---------------- launch ----------------

extern "C" void kernel_launch(void* const* d_in, const int* in_sizes, int n_in,
                              void* d_out, int out_size, void* d_ws, size_t ws_size,
                              hipStream_t stream) {
  const float* x  = (const float*)d_in[0];
  const float* w  = (const float*)d_in[1];
  const float* A  = (const float*)d_in[2];
  const float* Bm = (const float*)d_in[3];
  float* out = (float*)d_out;

  const size_t need = ((size_t)N_ROWS * K_DIM + (size_t)N_COLS * K_DIM) * sizeof(unsigned short);
  if (ws_size < need) {
    dim3 grid(N_COLS / 256, N_ROWS);
    fallback_kernel<<<grid, 256, 0, stream>>>(x, w, A, Bm, out);
    return;
  }

  unsigned short* xb = (unsigned short*)d_ws;
  unsigned short* wb = xb + (size_t)N_ROWS * K_DIM;

  prep_kernel<<<XBLK + WBLK, 256, 0, stream>>>(x, w, A, Bm, xb, wb);

  const int grid_gemm = (N_ROWS / 256) * (N_COLS / 256);   // 512
  gemm_bf16_r14<<<grid_gemm, 512, 0, stream>>>(xb, wb, out);
}

// Round 15
// 309.136 us; speedup vs baseline: 1.7341x; 1.1200x over previous
//
#include <hip/hip_runtime.h>

// LoRALinear: out[8192,4096] = x @ W.T + 2.0*(x@A.T)@B.T = x @ (W + 2*B@A).T
// One bf16 MFMA GEMM, 256x256 tile, 8 waves, ONE barrier per K-tile:
// {stage(t+1) -> free compiler-scheduled reads+MFMA -> lgkm(0) vmcnt(0) bar}.
// Session-best structure (R8): 247us GEMM, 0 bank conflicts, MfmaUtil ~50%.
// Seven structure variants (lookahead, fat-phase, 4-buf, 32x32, 2-block TLP,
// m201-reconstruction) all failed to beat it; locked in as final.

#define N_ROWS 8192
#define K_DIM  4096
#define N_COLS 4096
#define RANK   16
#define BK     64
#define NT     (K_DIM / BK)   // 64 K-tiles

#define XBLK ((N_ROWS * K_DIM / 4) / 256)   // 32768 blocks for x->bf16
#define WBLK ((N_COLS * K_DIM / 4) / 256)   // 16384 blocks for W_eff->bf16

typedef __bf16 bf16x8 __attribute__((ext_vector_type(8)));
typedef float  f32x4  __attribute__((ext_vector_type(4)));

__device__ __forceinline__ unsigned short f2bf(float f) {
  unsigned int u = __builtin_bit_cast(unsigned int, f);
  u += 0x7FFFu + ((u >> 16) & 1u);   // RNE
  return (unsigned short)(u >> 16);
}

// ---------------- fused conversion kernel ----------------

__global__ __launch_bounds__(256) void prep_kernel(const float* __restrict__ x,
                                                   const float* __restrict__ w,
                                                   const float* __restrict__ A,
                                                   const float* __restrict__ Bm,
                                                   unsigned short* __restrict__ xb,
                                                   unsigned short* __restrict__ wb) {
  const int b = blockIdx.x;
  if (b < XBLK) {
    size_t idx = (size_t)b * 256 + threadIdx.x;
    const float4 v = *reinterpret_cast<const float4*>(x + idx * 4);
    ushort4 r;
    r.x = f2bf(v.x); r.y = f2bf(v.y); r.z = f2bf(v.z); r.w = f2bf(v.w);
    *reinterpret_cast<ushort4*>(xb + idx * 4) = r;
  } else {
    size_t idx = (size_t)(b - XBLK) * 256 + threadIdx.x;
    int o  = (int)(idx >> 10);
    int ic = (int)(idx & 1023) << 2;
    const float4 wv = *reinterpret_cast<const float4*>(w + (size_t)o * K_DIM + ic);
    float a0 = wv.x, a1 = wv.y, a2 = wv.z, a3 = wv.w;
    float br[RANK];
#pragma unroll
    for (int r4 = 0; r4 < RANK / 4; ++r4) {
      const float4 bv = *reinterpret_cast<const float4*>(Bm + (size_t)o * RANK + r4 * 4);
      br[r4 * 4 + 0] = bv.x; br[r4 * 4 + 1] = bv.y;
      br[r4 * 4 + 2] = bv.z; br[r4 * 4 + 3] = bv.w;
    }
#pragma unroll
    for (int r = 0; r < RANK; ++r) {
      const float4 av = *reinterpret_cast<const float4*>(A + (size_t)r * K_DIM + ic);
      float b2 = br[r] * 2.0f;
      a0 += b2 * av.x; a1 += b2 * av.y; a2 += b2 * av.z; a3 += b2 * av.w;
    }
    ushort4 rr;
    rr.x = f2bf(a0); rr.y = f2bf(a1); rr.z = f2bf(a2); rr.w = f2bf(a3);
    *reinterpret_cast<ushort4*>(wb + (size_t)o * K_DIM + ic) = rr;
  }
}

// ---------------- GEMM ----------------
// LDS: A [buf][half][128 rows][64 k] bf16 at 0..64K; B same at 64K..128K.
// XOR swizzle within a half (16B granules): phys = logical ^ (row&7); staged
// via pre-swizzled global source (linear gload_lds dest), read w/ matching XOR.
// Per tile t (cbuf c, nbuf n):
//   stage A0,A1,B0,B1(t+1)->n (8 gloads, issue-first)
//   [compiler-scheduled] 24 ds_read_b128 from c + 64 MFMA, counted lgkmcnt
//   lgkm(0); vmcnt(0); s_barrier           <- the ONLY barrier per tile

__device__ __forceinline__ void gload_lds16(const void* g, void* l) {
  __builtin_amdgcn_global_load_lds(
      (__attribute__((address_space(1))) void*)g,
      (__attribute__((address_space(3))) void*)l, 16, 0, 0);
}

__global__ __launch_bounds__(512, 1) void gemm_bf16_r15(
    const unsigned short* __restrict__ xb, const unsigned short* __restrict__ wb,
    float* __restrict__ out) {
  __shared__ __align__(16) char smem[131072];

  const int t  = threadIdx.x;
  const int l  = t & 63;
  const int wv = t >> 6;
  const int lr = l & 15;
  const int lk = l >> 4;
  const int wr = wv >> 2;     // 0..1
  const int wc = wv & 3;      // 0..3

  // XCD-aware bijective swizzle: 512 blocks % 8 == 0
  const int bid  = blockIdx.x;
  const int sbid = (bid & 7) * 64 + (bid >> 3);
  const int bm   = sbid >> 4;   // 0..31
  const int bn   = sbid & 15;   // 0..15

  // staging: thread t -> row t>>3 (0..63), swizzled col granule
  const int srow = t >> 3;
  const int scol = ((t & 7) ^ ((t >> 3) & 7)) << 3;         // elements
  const unsigned short* gA = xb + (size_t)(bm * 256 + srow) * K_DIM + scol;
  const unsigned short* gB = wb + (size_t)(bn * 256 + srow) * K_DIM + scol;
  char* ldsA = smem + t * 16;
  char* ldsB = smem + 65536 + t * 16;

#define STG_A(hh, SRC, NB) do {                                                 \
    const unsigned short* _g = (SRC) + (size_t)((hh) * 128) * K_DIM;            \
    char* _l = ldsA + (NB) + (hh) * 16384;                                      \
    gload_lds16(_g, _l);                                                        \
    gload_lds16(_g + (size_t)64 * K_DIM, _l + 8192);                            \
  } while (0)
#define STG_B(hh, SRC, NB) do {                                                 \
    const unsigned short* _g = (SRC) + (size_t)((hh) * 128) * K_DIM;            \
    char* _l = ldsB + (NB) + (hh) * 16384;                                      \
    gload_lds16(_g, _l);                                                        \
    gload_lds16(_g + (size_t)64 * K_DIM, _l + 8192);                            \
  } while (0)

  // fragment LDS addressing (read-side XOR matches staged swizzle)
  const int g0   = (lk ^ (lr & 7)) << 4;
  const int g1   = ((lk + 4) ^ (lr & 7)) << 4;
  const int aoff = (wr * 16 + lr) * 128;
  const int boff = (wc * 16 + lr) * 128;

  bf16x8 aF[8];      // current A half (renamed by compiler across halves)
  bf16x8 bE[4];      // B0(t)
  bf16x8 bO[4];      // B1(t)
  f32x4 acc[8][4];
#pragma unroll
  for (int m = 0; m < 8; ++m)
#pragma unroll
    for (int n = 0; n < 4; ++n)
      acc[m][n] = (f32x4){0.f, 0.f, 0.f, 0.f};

#define RD_A(BASE) do {                                                         \
    _Pragma("unroll")                                                           \
    for (int m = 0; m < 4; ++m) {                                               \
      aF[2 * m + 0] = *(const bf16x8*)(smem + (BASE) + m * 4096 + aoff + g0);   \
      aF[2 * m + 1] = *(const bf16x8*)(smem + (BASE) + m * 4096 + aoff + g1);   \
    }                                                                           \
  } while (0)
#define RD_B(DST, BASE) do {                                                    \
    _Pragma("unroll")                                                           \
    for (int n = 0; n < 2; ++n) {                                               \
      DST[2 * n + 0] = *(const bf16x8*)(smem + 65536 + (BASE) + n * 8192 + boff + g0); \
      DST[2 * n + 1] = *(const bf16x8*)(smem + 65536 + (BASE) + n * 8192 + boff + g1); \
    }                                                                           \
  } while (0)

#define MFMA_Q(MB, NB0, BF) do {                                                \
    _Pragma("unroll")                                                           \
    for (int mi = 0; mi < 4; ++mi)                                              \
      _Pragma("unroll")                                                         \
      for (int ni = 0; ni < 2; ++ni)                                            \
        _Pragma("unroll")                                                       \
        for (int kk = 0; kk < 2; ++kk)                                          \
          acc[(MB) + mi][(NB0) + ni] = __builtin_amdgcn_mfma_f32_16x16x32_bf16( \
              aF[mi * 2 + kk], BF[ni * 2 + kk], acc[(MB) + mi][(NB0) + ni], 0, 0, 0); \
  } while (0)

#define TILE(CB, NB, T) do {                                                    \
    const int _t1 = ((T) + 1 < NT) ? (T) + 1 : NT - 1;                          \
    const unsigned short* _sA = gA + (size_t)_t1 * BK;                          \
    const unsigned short* _sB = gB + (size_t)_t1 * BK;                          \
    /* issue-first staging of t+1 into buf n */                                 \
    STG_A(0, _sA, NB); STG_A(1, _sA, NB);                                       \
    STG_B(0, _sB, NB); STG_B(1, _sB, NB);                                       \
    __builtin_amdgcn_sched_barrier(0);                                          \
    /* free interior: compiler interleaves reads & MFMAs w/ counted lgkmcnt */  \
    RD_A((CB));                                                                 \
    RD_B(bE, (CB));                                                             \
    RD_B(bO, (CB) + 16384);                                                     \
    MFMA_Q(0, 0, bE);                                                           \
    MFMA_Q(0, 2, bO);                                                           \
    RD_A((CB) + 16384);                                                         \
    MFMA_Q(4, 0, bE);                                                           \
    MFMA_Q(4, 2, bO);                                                           \
    /* tile-end fence: own reads drained, own stages landed, then barrier */    \
    asm volatile("s_waitcnt lgkmcnt(0)");                                       \
    __builtin_amdgcn_sched_barrier(0);                                          \
    asm volatile("s_waitcnt vmcnt(0)");                                         \
    __builtin_amdgcn_s_barrier();                                               \
    __builtin_amdgcn_sched_barrier(0);                                          \
  } while (0)

  // ---- prologue: stage tile0 -> buf0; drain; barrier ----
  STG_A(0, gA, 0); STG_A(1, gA, 0); STG_B(0, gB, 0); STG_B(1, gB, 0);
  __builtin_amdgcn_sched_barrier(0);
  asm volatile("s_waitcnt vmcnt(0)");
  __builtin_amdgcn_s_barrier();
  __builtin_amdgcn_sched_barrier(0);

#pragma nounroll
  for (int u = 0; u < NT / 2; ++u) {
    TILE(0, 32768, 2 * u);
    TILE(32768, 0, 2 * u + 1);
  }

  // ---- epilogue: C/D layout col=lane&15, row=(lane>>4)*4+j ----
  const int orow = bm * 256 + wr * 16 + lk * 4;
  const int ocol = bn * 256 + wc * 16 + lr;
#pragma unroll
  for (int mf = 0; mf < 8; ++mf)
#pragma unroll
    for (int nf = 0; nf < 4; ++nf)
#pragma unroll
      for (int j = 0; j < 4; ++j)
        out[(size_t)(orow + mf * 32 + j) * N_COLS + (ocol + nf * 64)] = acc[mf][nf][j];

#undef STG_A
#undef STG_B
#undef RD_A
#undef RD_B
#undef MFMA_Q
#undef TILE
}

// ---------------- exact fp32 fallback (ws too small) ----------------

__global__ __launch_bounds__(256) void fallback_kernel(const float* __restrict__ x,
                                                       const float* __restrict__ w,
                                                       const float* __restrict__ A,
                                                       const float* __restrict__ Bm,
                                                       float* __restrict__ out) {
  const int o    = blockIdx.x * 256 + threadIdx.x;
  const int nrow = blockIdx.y;
  float bro[RANK];
#pragma unroll
  for (int r = 0; r < RANK; ++r) bro[r] = Bm[(size_t)o * RANK + r] * 2.0f;
  float bacc = 0.f;
  float tacc[RANK];
#pragma unroll
  for (int r = 0; r < RANK; ++r) tacc[r] = 0.f;
  for (int k = 0; k < K_DIM; ++k) {
    float xv = x[(size_t)nrow * K_DIM + k];
    bacc += xv * w[(size_t)o * K_DIM + k];
#pragma unroll
    for (int r = 0; r < RANK; ++r) tacc[r] += xv * A[(size_t)r * K_DIM + k];
  }
  float res = bacc;
#pragma unroll
  for (int r = 0; r < RANK; ++r) res += bro[r] * tacc[r];
  out[(size_t)nrow * N_COLS + o] = res;
}

// ---------------- launch ----------------

extern "C" void kernel_launch(void* const* d_in, const int* in_sizes, int n_in,
                              void* d_out, int out_size, void* d_ws, size_t ws_size,
                              hipStream_t stream) {
  const float* x  = (const float*)d_in[0];
  const float* w  = (const float*)d_in[1];
  const float* A  = (const float*)d_in[2];
  const float* Bm = (const float*)d_in[3];
  float* out = (float*)d_out;

  const size_t need = ((size_t)N_ROWS * K_DIM + (size_t)N_COLS * K_DIM) * sizeof(unsigned short);
  if (ws_size < need) {
    dim3 grid(N_COLS / 256, N_ROWS);
    fallback_kernel<<<grid, 256, 0, stream>>>(x, w, A, Bm, out);
    return;
  }

  unsigned short* xb = (unsigned short*)d_ws;
  unsigned short* wb = xb + (size_t)N_ROWS * K_DIM;

  prep_kernel<<<XBLK + WBLK, 256, 0, stream>>>(x, w, A, Bm, xb, wb);

  const int grid_gemm = (N_ROWS / 256) * (N_COLS / 256);   // 512
  gemm_bf16_r15<<<grid_gemm, 512, 0, stream>>>(xb, wb, out);
}